// Round 16
// baseline (410.585 us; speedup 1.0000x reference)
//
#include <hip/hip_runtime.h>
#include <hip/hip_bf16.h>
#include <cstdio>
#include <cstdint>

// Problem constants (B=4, S=4096, D=2048)
#define NBIG 16384   // B*S
#define DDIM 2048
#define SPLITK 4     // gemm1 split-K

// 256^2 deep-pipelined GEMM geometry
#define BM 256
#define BN 256
#define BKT 64       // K-step per tile

typedef __attribute__((ext_vector_type(4))) float f32x4;
typedef __attribute__((ext_vector_type(16))) float f32x16;
typedef __attribute__((ext_vector_type(8))) short bf16x8;

__device__ __forceinline__ unsigned short f2bf(float f) {
  union { float f; unsigned u; } v; v.f = f;
  return (unsigned short)((v.u + 0x7FFFu + ((v.u >> 16) & 1u)) >> 16); // RN-even
}

// global -> LDS direct copy, 16 B per lane. LDS dest is wave-uniform base;
// HW writes base + lane*16. Global source IS per-lane (swizzle goes there).
__device__ __forceinline__ void gll16(const void* g, void* l) {
  auto gp = reinterpret_cast<const __attribute__((address_space(1))) unsigned int*>(
      reinterpret_cast<uintptr_t>(g));
  auto lp = reinterpret_cast<__attribute__((address_space(3))) unsigned int*>(
      (unsigned int)reinterpret_cast<uintptr_t>(l));
  __builtin_amdgcn_global_load_lds(gp, lp, 16, 0, 0);
}

__device__ __forceinline__ void waitvm8() { asm volatile("s_waitcnt vmcnt(8)" ::: "memory"); }
__device__ __forceinline__ void waitvm0() { asm volatile("s_waitcnt vmcnt(0)" ::: "memory"); }
__device__ __forceinline__ void barrier_pinned() {
  __builtin_amdgcn_sched_barrier(0);
  __builtin_amdgcn_s_barrier();
  __builtin_amdgcn_sched_barrier(0);
}

// bijective XCD swizzle (m204): all our GEMM grids have nwg % 8 == 0
__device__ __forceinline__ void xcd_swizzle(int& bx, int& by, int& bz) {
  const unsigned nx = gridDim.x, ny = gridDim.y;
  const unsigned nwg = nx * ny * gridDim.z;
  unsigned wg = blockIdx.x + nx * (blockIdx.y + ny * blockIdx.z);
  wg = (wg & 7u) * (nwg >> 3) + (wg >> 3);
  bx = wg % nx;
  unsigned r = wg / nx;
  by = r % ny;
  bz = r / ny;
}

// ---------------------------------------------------------------------------
// prep: 64x64 tiled transpose-convert f32 -> bf16.
//  blockIdx.y==0: k -> KT (D x NBIG) + K_bf (NBIG x D) + column-sum into ks
//  blockIdx.y==1: v -> VT (D x NBIG)
// ---------------------------------------------------------------------------
__global__ __launch_bounds__(256) void prep_kernel(
    const float* __restrict__ k, const float* __restrict__ v,
    unsigned short* __restrict__ KT, unsigned short* __restrict__ VT,
    unsigned short* __restrict__ Kbf, float* __restrict__ ks)
{
  __shared__ unsigned short sm[64][66];
  __shared__ float sks[64];
  const int t = threadIdx.x;
  const int tiles_d = DDIM / 64;
  const int n0 = (blockIdx.x / tiles_d) * 64;
  const int d0 = (blockIdx.x % tiles_d) * 64;
  const bool is_k = (blockIdx.y == 0);
  const float* __restrict__ src = is_k ? k : v;
  unsigned short* __restrict__ dstT = is_k ? KT : VT;

  const int r = t >> 4;         // 0..15
  const int c = (t & 15) * 4;   // 0..60

  if (t < 64) sks[t] = 0.f;
  __syncthreads();

  float a0 = 0.f, a1 = 0.f, a2 = 0.f, a3 = 0.f;
#pragma unroll
  for (int i = 0; i < 4; ++i) {
    const int row = i * 16 + r;
    f32x4 val = *reinterpret_cast<const f32x4*>(&src[(size_t)(n0 + row) * DDIM + d0 + c]);
    unsigned short b0 = f2bf(val.x), b1 = f2bf(val.y), b2 = f2bf(val.z), b3 = f2bf(val.w);
    sm[row][c + 0] = b0; sm[row][c + 1] = b1;
    sm[row][c + 2] = b2; sm[row][c + 3] = b3;
    if (is_k) {
      unsigned int p0 = (unsigned)b0 | ((unsigned)b1 << 16);
      unsigned int p1 = (unsigned)b2 | ((unsigned)b3 << 16);
      *reinterpret_cast<uint2*>(&Kbf[(size_t)(n0 + row) * DDIM + d0 + c]) = make_uint2(p0, p1);
      a0 += val.x; a1 += val.y; a2 += val.z; a3 += val.w;
    }
  }
  if (is_k) {
    atomicAdd(&sks[c + 0], a0);
    atomicAdd(&sks[c + 1], a1);
    atomicAdd(&sks[c + 2], a2);
    atomicAdd(&sks[c + 3], a3);
  }
  __syncthreads();

#pragma unroll
  for (int i = 0; i < 4; ++i) {
    const int rowp = i * 16 + r;
    unsigned int p0 = (unsigned)sm[c + 0][rowp] | ((unsigned)sm[c + 1][rowp] << 16);
    unsigned int p1 = (unsigned)sm[c + 2][rowp] | ((unsigned)sm[c + 3][rowp] << 16);
    *reinterpret_cast<uint2*>(&dstT[(size_t)(d0 + rowp) * NBIG + n0 + c]) = make_uint2(p0, p1);
  }
  if (is_k && t < 64) atomicAdd(&ks[d0 + t], sks[t]);
}

__global__ void init_ks_kernel(const float* __restrict__ ksum, float* __restrict__ ks) {
  int i = blockIdx.x * 256 + threadIdx.x;
  if (i < DDIM) ks[i] = ksum[i];
}

// ---------------------------------------------------------------------------
// gemm256: 256x256 tile, BK=64, 8 waves (2Mx4N), double-buffered LDS with
// half-tile ring staging + counted vmcnt(8) + T2 swizzle + T5 setprio
// + T1 XCD block swizzle. R7 coarse 3-barrier schedule (measured best), now
// with 32x32x16 MFMA (m119: 2495 vs 2176 TF -> ~15% faster matrix pipe,
// 4x fewer MFMA issue slots). Per-wave tile 128x64 = 4x2 of 32x32 tiles.
// A-frag: lane row=l&31, k=(l>>5)*8; slot swizzle ((ks*2+hi2)^(l&7)) keeps
// 8-accesses/bank balance (conflict-free). C/D: col=lane&31,
// row=(reg&3)+8*(reg>>2)+4*(lane>>5)  [m74/m101].
// BF16OUT: epilogue emits bf16 (gemm1 split partials) else f32 (gemm2 ctx).
// ---------------------------------------------------------------------------
template <bool BF16OUT>
__global__ __launch_bounds__(512, 2) void gemm256_kernel(
    const unsigned short* __restrict__ A, const unsigned short* __restrict__ B,
    void* __restrict__ Cv, int lda, int ldb, int kchunk, long long zstride)
{
  __shared__ unsigned short Abuf[2][BM * BKT];   // 32 KiB per buffer
  __shared__ unsigned short Bbuf[2][BN * BKT];   // total 128 KiB

  int bx, by, bz;
  xcd_swizzle(bx, by, bz);

  const int t = threadIdx.x, lane = t & 63, w = t >> 6;
  const int wm = w >> 2, wn = w & 3;            // 2 x 4 wave grid
  const int m0 = by * BM, n0 = bx * BN;
  const int kbeg = bz * kchunk;
  const int NT = kchunk / BKT;                  // 64 (gemm1) / 32 (gemm2)

  // staging: lane covers row (l>>3), swizzled source granule (l&7)^(l>>3)
  const int srow = lane >> 3;
  const int sgr  = (lane & 7) ^ srow;
  const unsigned short* Ag = A + (size_t)(m0 + srow) * lda + kbeg + sgr * 8;
  const unsigned short* Bg = B + (size_t)(n0 + srow) * ldb + kbeg + sgr * 8;

  // 32x32 fragment addressing: row = l&31, k-granule = ks*2 + (l>>5),
  // fetched slot = granule ^ (row&7) = granule ^ (l&7)
  const int l31 = lane & 31;
  const int hi2 = lane >> 5;             // 0..1
  const int lo7 = lane & 7;
  const int arow = (wm * 128 + l31) * BKT;
  const int brow = (wn * 64 + l31) * BKT;

  // stage one half (128 rows) of an operand tile: 2 x gll16 per thread
  auto stage_op = [&](const unsigned short* G, unsigned short* Lbase, int ld_,
                      int kt, int half) {
    const unsigned short* g = G + (size_t)(half * 128 + w * 16) * ld_ + (size_t)kt * BKT;
    unsigned short* l = Lbase + (half * 128 + w * 16) * BKT;
    gll16(g, l);
    gll16(g + (size_t)8 * ld_, l + 8 * BKT);
  };

  // prologue: stage tiles 0 and 1 (8 loads/thread each)
  stage_op(Bg, Bbuf[0], ldb, 0, 0); stage_op(Bg, Bbuf[0], ldb, 0, 1);
  stage_op(Ag, Abuf[0], lda, 0, 0); stage_op(Ag, Abuf[0], lda, 0, 1);
  stage_op(Bg, Bbuf[1], ldb, 1, 0); stage_op(Bg, Bbuf[1], ldb, 1, 1);
  stage_op(Ag, Abuf[1], lda, 1, 0); stage_op(Ag, Abuf[1], lda, 1, 1);
  waitvm8();                       // tile 0 complete; tile 1 in flight
  __builtin_amdgcn_s_barrier();
  __builtin_amdgcn_sched_barrier(0);

  f32x16 acc[4][2] = {};   // [tm 32-row block][tn 32-col block]

#pragma unroll 2
  for (int tl = 0; tl < NT; ++tl) {
    const int q = tl & 1;
    const unsigned short* Al = Abuf[q];
    const unsigned short* Bl = Bbuf[q];
    bf16x8 af[2][4], bA[4], bB[4];

    // ---- P1: read af(tm0-1, ks0-3) + bA(tn0) -> MFMA acc[0-1][0]
#pragma unroll
    for (int ks = 0; ks < 4; ++ks) {
      const int swz = ((ks * 2 + hi2) ^ lo7) * 8;
      af[0][ks] = *reinterpret_cast<const bf16x8*>(Al + arow + 0 * 32 * BKT + swz);
      af[1][ks] = *reinterpret_cast<const bf16x8*>(Al + arow + 1 * 32 * BKT + swz);
      bA[ks]    = *reinterpret_cast<const bf16x8*>(Bl + brow + 0 * 32 * BKT + swz);
    }
    __builtin_amdgcn_s_setprio(1);
#pragma unroll
    for (int ks = 0; ks < 4; ++ks)
#pragma unroll
      for (int tm = 0; tm < 2; ++tm)
        acc[tm][0] = __builtin_amdgcn_mfma_f32_32x32x16_bf16(af[tm][ks], bA[ks], acc[tm][0], 0, 0, 0);
    __builtin_amdgcn_s_setprio(0);

    // ---- P2: read bB(tn1) -> MFMA acc[0-1][1]
#pragma unroll
    for (int ks = 0; ks < 4; ++ks) {
      const int swz = ((ks * 2 + hi2) ^ lo7) * 8;
      bB[ks] = *reinterpret_cast<const bf16x8*>(Bl + brow + 1 * 32 * BKT + swz);
    }
    __builtin_amdgcn_s_setprio(1);
#pragma unroll
    for (int ks = 0; ks < 4; ++ks)
#pragma unroll
      for (int tm = 0; tm < 2; ++tm)
        acc[tm][1] = __builtin_amdgcn_mfma_f32_32x32x16_bf16(af[tm][ks], bB[ks], acc[tm][1], 0, 0, 0);
    __builtin_amdgcn_s_setprio(0);
    barrier_pinned();   // end P2: B(tile tl) fully read by all waves

    // ---- P3: stage (tl+2).B; read af(tm2-3) -> MFMA acc[2-3][0]
    if (tl + 2 < NT) {
      stage_op(Bg, Bbuf[q], ldb, tl + 2, 0);
      stage_op(Bg, Bbuf[q], ldb, tl + 2, 1);
    }
#pragma unroll
    for (int ks = 0; ks < 4; ++ks) {
      const int swz = ((ks * 2 + hi2) ^ lo7) * 8;
      af[0][ks] = *reinterpret_cast<const bf16x8*>(Al + arow + 2 * 32 * BKT + swz);
      af[1][ks] = *reinterpret_cast<const bf16x8*>(Al + arow + 3 * 32 * BKT + swz);
    }
    __builtin_amdgcn_s_setprio(1);
#pragma unroll
    for (int ks = 0; ks < 4; ++ks)
#pragma unroll
      for (int tm = 0; tm < 2; ++tm)
        acc[2 + tm][0] = __builtin_amdgcn_mfma_f32_32x32x16_bf16(af[tm][ks], bA[ks], acc[2 + tm][0], 0, 0, 0);
    __builtin_amdgcn_s_setprio(0);
    barrier_pinned();   // end P3: A(tile tl) fully read by all waves

    // ---- P4: stage (tl+2).A; MFMA acc[2-3][1]; counted wait
    if (tl + 2 < NT) {
      stage_op(Ag, Abuf[q], lda, tl + 2, 0);
      stage_op(Ag, Abuf[q], lda, tl + 2, 1);
    }
    __builtin_amdgcn_s_setprio(1);
#pragma unroll
    for (int ks = 0; ks < 4; ++ks)
#pragma unroll
      for (int tm = 0; tm < 2; ++tm)
        acc[2 + tm][1] = __builtin_amdgcn_mfma_f32_32x32x16_bf16(af[tm][ks], bB[ks], acc[2 + tm][1], 0, 0, 0);
    __builtin_amdgcn_s_setprio(0);
    if (tl + 1 < NT) {
      if (tl + 2 < NT) waitvm8();   // next tile's loads retired; newest 8 in flight
      else             waitvm0();   // pipeline tail: drain
      __builtin_amdgcn_s_barrier();
      __builtin_amdgcn_sched_barrier(0);
    }
  }

  // epilogue: 32x32 C/D layout col=lane&31, row=(reg&3)+8*(reg>>2)+4*(lane>>5)
  const int crow0 = m0 + wm * 128 + 4 * hi2;
  const int ccol0 = n0 + wn * 64 + l31;
  if (BF16OUT) {
    unsigned short* Cz = (unsigned short*)Cv + (size_t)bz * zstride;
#pragma unroll
    for (int tm = 0; tm < 4; ++tm)
#pragma unroll
      for (int tn = 0; tn < 2; ++tn)
#pragma unroll
        for (int j = 0; j < 16; ++j) {
          const int row = crow0 + tm * 32 + (j & 3) + 8 * (j >> 2);
          Cz[(size_t)row * DDIM + ccol0 + tn * 32] = f2bf(acc[tm][tn][j]);
        }
  } else {
    float* Cz = (float*)Cv + (size_t)bz * zstride;
#pragma unroll
    for (int tm = 0; tm < 4; ++tm)
#pragma unroll
      for (int tn = 0; tn < 2; ++tn)
#pragma unroll
        for (int j = 0; j < 16; ++j) {
          const int row = crow0 + tm * 32 + (j & 3) + 8 * (j >> 2);
          Cz[(size_t)row * DDIM + ccol0 + tn * 32] = acc[tm][tn][j];
        }
  }
}

// kv_bf[i] = bf16(kv_state[i] + sum_z bf16_partial[z][i])
__global__ __launch_bounds__(256) void kvconv_kernel(
    const unsigned short* __restrict__ kvp, const float* __restrict__ kvst,
    unsigned short* __restrict__ kvbf)
{
  size_t i = ((size_t)blockIdx.x * 256 + threadIdx.x) * 4;
  f32x4 s = *reinterpret_cast<const f32x4*>(&kvst[i]);
#pragma unroll
  for (int z = 0; z < SPLITK; ++z) {
    ushort4 p = *reinterpret_cast<const ushort4*>(&kvp[(size_t)z * DDIM * DDIM + i]);
    union { unsigned u; float f; } c0, c1, c2, c3;
    c0.u = (unsigned)p.x << 16; c1.u = (unsigned)p.y << 16;
    c2.u = (unsigned)p.z << 16; c3.u = (unsigned)p.w << 16;
    s.x += c0.f; s.y += c1.f; s.z += c2.f; s.w += c3.f;
  }
  unsigned int p0 = (unsigned)f2bf(s.x) | ((unsigned)f2bf(s.y) << 16);
  unsigned int p1 = (unsigned)f2bf(s.z) | ((unsigned)f2bf(s.w) << 16);
  *reinterpret_cast<uint2*>(&kvbf[i]) = make_uint2(p0, p1);
}

// normalizer[n] = sum_d Kbf[n,d] * ks_new[d]  (bf16 k, f32 ks; wave per row)
__global__ __launch_bounds__(256) void norm_kernel(
    const unsigned short* __restrict__ Kbf, const float* __restrict__ ks,
    float* __restrict__ out)
{
  const int lane = threadIdx.x & 63;
  const int w = threadIdx.x >> 6;
  const int row = blockIdx.x * 4 + w;
  const unsigned short* kr = Kbf + (size_t)row * DDIM;
  float s = 0.f;
#pragma unroll
  for (int i = 0; i < 4; ++i) {
    bf16x8 a = *reinterpret_cast<const bf16x8*>(&kr[i * 512 + lane * 8]);
    f32x4 b0 = *reinterpret_cast<const f32x4*>(&ks[i * 512 + lane * 8]);
    f32x4 b1 = *reinterpret_cast<const f32x4*>(&ks[i * 512 + lane * 8 + 4]);
    float af[8];
#pragma unroll
    for (int j = 0; j < 8; ++j) {
      union { unsigned u; float f; } cv;
      cv.u = ((unsigned)(unsigned short)a[j]) << 16;
      af[j] = cv.f;
    }
    s += af[0] * b0.x + af[1] * b0.y + af[2] * b0.z + af[3] * b0.w
       + af[4] * b1.x + af[5] * b1.y + af[6] * b1.z + af[7] * b1.w;
  }
  for (int off = 32; off; off >>= 1) s += __shfl_down(s, off, 64);
  if (lane == 0) out[row] = s;
}

extern "C" void kernel_launch(void* const* d_in, const int* in_sizes, int n_in,
                              void* d_out, int out_size, void* d_ws, size_t ws_size,
                              hipStream_t stream) {
  const float* k    = (const float*)d_in[0];
  const float* v    = (const float*)d_in[1];
  const float* kvst = (const float*)d_in[2];
  const float* ksum = (const float*)d_in[3];

  // ws layout: KT (64Mi) | VT (64Mi) | K_bf (64Mi) | kv_bf (8Mi) | ks (8Ki)
  const size_t SZ_T = (size_t)DDIM * NBIG * 2;
  const size_t WS_NEED = SZ_T * 3 + (size_t)DDIM * DDIM * 2 + DDIM * 4;
  if (ws_size < WS_NEED) {
    fprintf(stderr, "kernel_launch: ws too small %zu < %zu\n", ws_size, WS_NEED);
    return;
  }
  char* ws = (char*)d_ws;
  unsigned short* KT   = (unsigned short*)ws;
  unsigned short* VT   = (unsigned short*)(ws + SZ_T);
  unsigned short* Kbf  = (unsigned short*)(ws + 2 * SZ_T);
  unsigned short* KVbf = (unsigned short*)(ws + 3 * SZ_T);
  float* ks            = (float*)(ws + 3 * SZ_T + (size_t)DDIM * DDIM * 2);

  float* ctx = (float*)d_out;
  float* nrm = ctx + (size_t)NBIG * DDIM;
  unsigned short* kvp = (unsigned short*)d_out;  // 32 MiB of bf16 partials in
                                                 // d_out scratch, overwritten by gemm2

  init_ks_kernel<<<(DDIM + 255) / 256, 256, 0, stream>>>(ksum, ks);
  prep_kernel<<<dim3((NBIG / 64) * (DDIM / 64), 2), 256, 0, stream>>>(k, v, KT, VT, Kbf, ks);
  // gemm1: bf16 kv partials = K^T V  (A=KT, B=VT, lda=ldb=NBIG, K-chunks of 4096)
  gemm256_kernel<true><<<dim3(DDIM / BN, DDIM / BM, SPLITK), 512, 0, stream>>>(
      KT, VT, kvp, NBIG, NBIG, NBIG / SPLITK, (long long)DDIM * DDIM);
  kvconv_kernel<<<(DDIM * DDIM) / (256 * 4), 256, 0, stream>>>(kvp, kvst, KVbf);
  // gemm2: ctx = K kv_new^T  (A=Kbf, B=KVbf, lda=ldb=DDIM, single K-chunk)
  gemm256_kernel<false><<<dim3(DDIM / BN, NBIG / BM, 1), 512, 0, stream>>>(
      Kbf, KVbf, ctx, DDIM, DDIM, DDIM, 0);
  norm_kernel<<<NBIG / 4, 256, 0, stream>>>(Kbf, ks, nrm);
}

// Round 17
// 377.740 us; speedup vs baseline: 1.0870x; 1.0870x over previous
//
#include <hip/hip_runtime.h>
#include <hip/hip_bf16.h>
#include <cstdio>
#include <cstdint>

// Problem constants (B=4, S=4096, D=2048)
#define NBIG 16384   // B*S
#define DDIM 2048
#define SPLITK 4     // gemm1 split-K

// 256^2 deep-pipelined GEMM geometry
#define BM 256
#define BN 256
#define BKT 64       // K-step per tile

typedef __attribute__((ext_vector_type(4))) float f32x4;
typedef __attribute__((ext_vector_type(8))) short bf16x8;

__device__ __forceinline__ unsigned short f2bf(float f) {
  union { float f; unsigned u; } v; v.f = f;
  return (unsigned short)((v.u + 0x7FFFu + ((v.u >> 16) & 1u)) >> 16); // RN-even
}

// global -> LDS direct copy, 16 B per lane. LDS dest is wave-uniform base;
// HW writes base + lane*16. Global source IS per-lane (swizzle goes there).
__device__ __forceinline__ void gll16(const void* g, void* l) {
  auto gp = reinterpret_cast<const __attribute__((address_space(1))) unsigned int*>(
      reinterpret_cast<uintptr_t>(g));
  auto lp = reinterpret_cast<__attribute__((address_space(3))) unsigned int*>(
      (unsigned int)reinterpret_cast<uintptr_t>(l));
  __builtin_amdgcn_global_load_lds(gp, lp, 16, 0, 0);
}

__device__ __forceinline__ void waitvm8() { asm volatile("s_waitcnt vmcnt(8)" ::: "memory"); }
__device__ __forceinline__ void waitvm0() { asm volatile("s_waitcnt vmcnt(0)" ::: "memory"); }
__device__ __forceinline__ void barrier_pinned() {
  __builtin_amdgcn_sched_barrier(0);
  __builtin_amdgcn_s_barrier();
  __builtin_amdgcn_sched_barrier(0);
}

// bijective XCD swizzle (m204): all our GEMM grids have nwg % 8 == 0
__device__ __forceinline__ void xcd_swizzle(int& bx, int& by, int& bz) {
  const unsigned nx = gridDim.x, ny = gridDim.y;
  const unsigned nwg = nx * ny * gridDim.z;
  unsigned wg = blockIdx.x + nx * (blockIdx.y + ny * blockIdx.z);
  wg = (wg & 7u) * (nwg >> 3) + (wg >> 3);
  bx = wg % nx;
  unsigned r = wg / nx;
  by = r % ny;
  bz = r / ny;
}

// ---------------------------------------------------------------------------
// prep: 64x64 tiled transpose-convert f32 -> bf16.
//  blockIdx.y==0: k -> KT (D x NBIG) + K_bf (NBIG x D) + column-sum into ks
//  blockIdx.y==1: v -> VT (D x NBIG)
// ---------------------------------------------------------------------------
__global__ __launch_bounds__(256) void prep_kernel(
    const float* __restrict__ k, const float* __restrict__ v,
    unsigned short* __restrict__ KT, unsigned short* __restrict__ VT,
    unsigned short* __restrict__ Kbf, float* __restrict__ ks)
{
  __shared__ unsigned short sm[64][66];
  __shared__ float sks[64];
  const int t = threadIdx.x;
  const int tiles_d = DDIM / 64;
  const int n0 = (blockIdx.x / tiles_d) * 64;
  const int d0 = (blockIdx.x % tiles_d) * 64;
  const bool is_k = (blockIdx.y == 0);
  const float* __restrict__ src = is_k ? k : v;
  unsigned short* __restrict__ dstT = is_k ? KT : VT;

  const int r = t >> 4;         // 0..15
  const int c = (t & 15) * 4;   // 0..60

  if (t < 64) sks[t] = 0.f;
  __syncthreads();

  float a0 = 0.f, a1 = 0.f, a2 = 0.f, a3 = 0.f;
#pragma unroll
  for (int i = 0; i < 4; ++i) {
    const int row = i * 16 + r;
    f32x4 val = *reinterpret_cast<const f32x4*>(&src[(size_t)(n0 + row) * DDIM + d0 + c]);
    unsigned short b0 = f2bf(val.x), b1 = f2bf(val.y), b2 = f2bf(val.z), b3 = f2bf(val.w);
    sm[row][c + 0] = b0; sm[row][c + 1] = b1;
    sm[row][c + 2] = b2; sm[row][c + 3] = b3;
    if (is_k) {
      unsigned int p0 = (unsigned)b0 | ((unsigned)b1 << 16);
      unsigned int p1 = (unsigned)b2 | ((unsigned)b3 << 16);
      *reinterpret_cast<uint2*>(&Kbf[(size_t)(n0 + row) * DDIM + d0 + c]) = make_uint2(p0, p1);
      a0 += val.x; a1 += val.y; a2 += val.z; a3 += val.w;
    }
  }
  if (is_k) {
    atomicAdd(&sks[c + 0], a0);
    atomicAdd(&sks[c + 1], a1);
    atomicAdd(&sks[c + 2], a2);
    atomicAdd(&sks[c + 3], a3);
  }
  __syncthreads();

#pragma unroll
  for (int i = 0; i < 4; ++i) {
    const int rowp = i * 16 + r;
    unsigned int p0 = (unsigned)sm[c + 0][rowp] | ((unsigned)sm[c + 1][rowp] << 16);
    unsigned int p1 = (unsigned)sm[c + 2][rowp] | ((unsigned)sm[c + 3][rowp] << 16);
    *reinterpret_cast<uint2*>(&dstT[(size_t)(d0 + rowp) * NBIG + n0 + c]) = make_uint2(p0, p1);
  }
  if (is_k && t < 64) atomicAdd(&ks[d0 + t], sks[t]);
}

__global__ void init_ks_kernel(const float* __restrict__ ksum, float* __restrict__ ks) {
  int i = blockIdx.x * 256 + threadIdx.x;
  if (i < DDIM) ks[i] = ksum[i];
}

// ---------------------------------------------------------------------------
// gemm256: 256x256 tile, BK=64, 8 waves (2Mx4N), double-buffered LDS with
// half-tile ring staging + counted vmcnt(8) + T2 swizzle + T5 setprio
// + T1 XCD block swizzle. R7 coarse 3-barrier schedule (measured best) with
// k-outer MFMA ordering (dependent same-acc MFMAs 8 issues apart, not 1).
// BF16OUT: epilogue emits bf16 (gemm1 split partials) else f32 (gemm2 ctx).
// ---------------------------------------------------------------------------
template <bool BF16OUT>
__global__ __launch_bounds__(512, 2) void gemm256_kernel(
    const unsigned short* __restrict__ A, const unsigned short* __restrict__ B,
    void* __restrict__ Cv, int lda, int ldb, int kchunk, long long zstride)
{
  __shared__ unsigned short Abuf[2][BM * BKT];   // 32 KiB per buffer
  __shared__ unsigned short Bbuf[2][BN * BKT];   // total 128 KiB

  int bx, by, bz;
  xcd_swizzle(bx, by, bz);

  const int t = threadIdx.x, lane = t & 63, w = t >> 6;
  const int wm = w >> 2, wn = w & 3;            // 2 x 4 wave grid
  const int m0 = by * BM, n0 = bx * BN;
  const int kbeg = bz * kchunk;
  const int NT = kchunk / BKT;                  // 64 (gemm1) / 32 (gemm2)

  // staging: lane covers row (l>>3), swizzled source granule (l&7)^(l>>3)
  const int srow = lane >> 3;
  const int sgr  = (lane & 7) ^ srow;
  const unsigned short* Ag = A + (size_t)(m0 + srow) * lda + kbeg + sgr * 8;
  const unsigned short* Bg = B + (size_t)(n0 + srow) * ldb + kbeg + sgr * 8;

  // read-side swizzle constants: logical granule kk*4+hi, fetch slot ^=(row&7)
  const int hi = lane >> 4;              // 0..3
  const int lo7 = lane & 7;              // == row&7 for frag rows
  const int swz0 = ((0 + hi) ^ lo7) * 8; // kk=0, short offset
  const int swz1 = ((4 + hi) ^ lo7) * 8; // kk=1
  const int arow = (wm * 128 + (lane & 15)) * BKT;
  const int brow = (wn * 64 + (lane & 15)) * BKT;

  // stage one half (128 rows) of an operand tile: 2 x gll16 per thread
  auto stage_op = [&](const unsigned short* G, unsigned short* Lbase, int ld_,
                      int kt, int half) {
    const unsigned short* g = G + (size_t)(half * 128 + w * 16) * ld_ + (size_t)kt * BKT;
    unsigned short* l = Lbase + (half * 128 + w * 16) * BKT;
    gll16(g, l);
    gll16(g + (size_t)8 * ld_, l + 8 * BKT);
  };

  // prologue: stage tiles 0 and 1 (8 loads/thread each)
  stage_op(Bg, Bbuf[0], ldb, 0, 0); stage_op(Bg, Bbuf[0], ldb, 0, 1);
  stage_op(Ag, Abuf[0], lda, 0, 0); stage_op(Ag, Abuf[0], lda, 0, 1);
  stage_op(Bg, Bbuf[1], ldb, 1, 0); stage_op(Bg, Bbuf[1], ldb, 1, 1);
  stage_op(Ag, Abuf[1], lda, 1, 0); stage_op(Ag, Abuf[1], lda, 1, 1);
  waitvm8();                       // tile 0 complete; tile 1 in flight
  __builtin_amdgcn_s_barrier();
  __builtin_amdgcn_sched_barrier(0);

  f32x4 acc[8][4] = {};

#pragma unroll 2
  for (int tl = 0; tl < NT; ++tl) {
    const int q = tl & 1;
    const unsigned short* Al = Abuf[q];
    const unsigned short* Bl = Bbuf[q];
    bf16x8 af[4][2], bA[2][2], bB[2][2];

    // ---- P1: a0-3 + b0-1 -> quadrant (m0-3, n0-1), k-outer
#pragma unroll
    for (int m = 0; m < 4; ++m) {
      af[m][0] = *reinterpret_cast<const bf16x8*>(Al + arow + m * 16 * BKT + swz0);
      af[m][1] = *reinterpret_cast<const bf16x8*>(Al + arow + m * 16 * BKT + swz1);
    }
#pragma unroll
    for (int n = 0; n < 2; ++n) {
      bA[n][0] = *reinterpret_cast<const bf16x8*>(Bl + brow + n * 16 * BKT + swz0);
      bA[n][1] = *reinterpret_cast<const bf16x8*>(Bl + brow + n * 16 * BKT + swz1);
    }
    __builtin_amdgcn_s_setprio(1);
#pragma unroll
    for (int kk = 0; kk < 2; ++kk)
#pragma unroll
      for (int m = 0; m < 4; ++m)
#pragma unroll
        for (int n = 0; n < 2; ++n)
          acc[m][n] = __builtin_amdgcn_mfma_f32_16x16x32_bf16(af[m][kk], bA[n][kk], acc[m][n], 0, 0, 0);
    __builtin_amdgcn_s_setprio(0);

    // ---- P2: b2-3 -> quadrant (m0-3, n2-3), k-outer
#pragma unroll
    for (int n = 0; n < 2; ++n) {
      bB[n][0] = *reinterpret_cast<const bf16x8*>(Bl + brow + (32 + n * 16) * BKT + swz0);
      bB[n][1] = *reinterpret_cast<const bf16x8*>(Bl + brow + (32 + n * 16) * BKT + swz1);
    }
    __builtin_amdgcn_s_setprio(1);
#pragma unroll
    for (int kk = 0; kk < 2; ++kk)
#pragma unroll
      for (int m = 0; m < 4; ++m)
#pragma unroll
        for (int n = 0; n < 2; ++n)
          acc[m][2 + n] = __builtin_amdgcn_mfma_f32_16x16x32_bf16(af[m][kk], bB[n][kk], acc[m][2 + n], 0, 0, 0);
    __builtin_amdgcn_s_setprio(0);
    barrier_pinned();   // end P2: B(tile tl) fully read by all waves

    // ---- P3: stage (tl+2).B into this buffer; a4-7 -> quadrant (m4-7, n0-1)
    if (tl + 2 < NT) {
      stage_op(Bg, Bbuf[q], ldb, tl + 2, 0);
      stage_op(Bg, Bbuf[q], ldb, tl + 2, 1);
    }
#pragma unroll
    for (int m = 0; m < 4; ++m) {
      af[m][0] = *reinterpret_cast<const bf16x8*>(Al + arow + (64 + m * 16) * BKT + swz0);
      af[m][1] = *reinterpret_cast<const bf16x8*>(Al + arow + (64 + m * 16) * BKT + swz1);
    }
    __builtin_amdgcn_s_setprio(1);
#pragma unroll
    for (int kk = 0; kk < 2; ++kk)
#pragma unroll
      for (int m = 0; m < 4; ++m)
#pragma unroll
        for (int n = 0; n < 2; ++n)
          acc[4 + m][n] = __builtin_amdgcn_mfma_f32_16x16x32_bf16(af[m][kk], bA[n][kk], acc[4 + m][n], 0, 0, 0);
    __builtin_amdgcn_s_setprio(0);
    barrier_pinned();   // end P3: A(tile tl) fully read by all waves

    // ---- P4: stage (tl+2).A; quadrant (m4-7, n2-3), k-outer; counted wait
    if (tl + 2 < NT) {
      stage_op(Ag, Abuf[q], lda, tl + 2, 0);
      stage_op(Ag, Abuf[q], lda, tl + 2, 1);
    }
    __builtin_amdgcn_s_setprio(1);
#pragma unroll
    for (int kk = 0; kk < 2; ++kk)
#pragma unroll
      for (int m = 0; m < 4; ++m)
#pragma unroll
        for (int n = 0; n < 2; ++n)
          acc[4 + m][2 + n] = __builtin_amdgcn_mfma_f32_16x16x32_bf16(af[m][kk], bB[n][kk], acc[4 + m][2 + n], 0, 0, 0);
    __builtin_amdgcn_s_setprio(0);
    if (tl + 1 < NT) {
      if (tl + 2 < NT) waitvm8();   // next tile's loads retired; newest 8 in flight
      else             waitvm0();   // pipeline tail: drain
      __builtin_amdgcn_s_barrier();
      __builtin_amdgcn_sched_barrier(0);
    }
  }

  // epilogue: C/D layout col=lane&15, row=hi*4+j
  const int crow0 = m0 + wm * 128 + hi * 4;
  const int ccol0 = n0 + wn * 64 + (lane & 15);
  if (BF16OUT) {
    unsigned short* Cz = (unsigned short*)Cv + (size_t)bz * zstride;
#pragma unroll
    for (int m = 0; m < 8; ++m)
#pragma unroll
      for (int n = 0; n < 4; ++n)
#pragma unroll
        for (int j = 0; j < 4; ++j)
          Cz[(size_t)(crow0 + m * 16 + j) * DDIM + ccol0 + n * 16] = f2bf(acc[m][n][j]);
  } else {
    float* Cz = (float*)Cv + (size_t)bz * zstride;
#pragma unroll
    for (int m = 0; m < 8; ++m)
#pragma unroll
      for (int n = 0; n < 4; ++n)
#pragma unroll
        for (int j = 0; j < 4; ++j)
          Cz[(size_t)(crow0 + m * 16 + j) * DDIM + ccol0 + n * 16] = acc[m][n][j];
  }
}

// kv_bf[i] = bf16(kv_state[i] + sum_z bf16_partial[z][i])
__global__ __launch_bounds__(256) void kvconv_kernel(
    const unsigned short* __restrict__ kvp, const float* __restrict__ kvst,
    unsigned short* __restrict__ kvbf)
{
  size_t i = ((size_t)blockIdx.x * 256 + threadIdx.x) * 4;
  f32x4 s = *reinterpret_cast<const f32x4*>(&kvst[i]);
#pragma unroll
  for (int z = 0; z < SPLITK; ++z) {
    ushort4 p = *reinterpret_cast<const ushort4*>(&kvp[(size_t)z * DDIM * DDIM + i]);
    union { unsigned u; float f; } c0, c1, c2, c3;
    c0.u = (unsigned)p.x << 16; c1.u = (unsigned)p.y << 16;
    c2.u = (unsigned)p.z << 16; c3.u = (unsigned)p.w << 16;
    s.x += c0.f; s.y += c1.f; s.z += c2.f; s.w += c3.f;
  }
  unsigned int p0 = (unsigned)f2bf(s.x) | ((unsigned)f2bf(s.y) << 16);
  unsigned int p1 = (unsigned)f2bf(s.z) | ((unsigned)f2bf(s.w) << 16);
  *reinterpret_cast<uint2*>(&kvbf[i]) = make_uint2(p0, p1);
}

// normalizer[n] = sum_d Kbf[n,d] * ks_new[d]  (bf16 k, f32 ks; wave per row)
__global__ __launch_bounds__(256) void norm_kernel(
    const unsigned short* __restrict__ Kbf, const float* __restrict__ ks,
    float* __restrict__ out)
{
  const int lane = threadIdx.x & 63;
  const int w = threadIdx.x >> 6;
  const int row = blockIdx.x * 4 + w;
  const unsigned short* kr = Kbf + (size_t)row * DDIM;
  float s = 0.f;
#pragma unroll
  for (int i = 0; i < 4; ++i) {
    bf16x8 a = *reinterpret_cast<const bf16x8*>(&kr[i * 512 + lane * 8]);
    f32x4 b0 = *reinterpret_cast<const f32x4*>(&ks[i * 512 + lane * 8]);
    f32x4 b1 = *reinterpret_cast<const f32x4*>(&ks[i * 512 + lane * 8 + 4]);
    float af[8];
#pragma unroll
    for (int j = 0; j < 8; ++j) {
      union { unsigned u; float f; } cv;
      cv.u = ((unsigned)(unsigned short)a[j]) << 16;
      af[j] = cv.f;
    }
    s += af[0] * b0.x + af[1] * b0.y + af[2] * b0.z + af[3] * b0.w
       + af[4] * b1.x + af[5] * b1.y + af[6] * b1.z + af[7] * b1.w;
  }
  for (int off = 32; off; off >>= 1) s += __shfl_down(s, off, 64);
  if (lane == 0) out[row] = s;
}

extern "C" void kernel_launch(void* const* d_in, const int* in_sizes, int n_in,
                              void* d_out, int out_size, void* d_ws, size_t ws_size,
                              hipStream_t stream) {
  const float* k    = (const float*)d_in[0];
  const float* v    = (const float*)d_in[1];
  const float* kvst = (const float*)d_in[2];
  const float* ksum = (const float*)d_in[3];

  // ws layout: KT (64Mi) | VT (64Mi) | K_bf (64Mi) | kv_bf (8Mi) | ks (8Ki)
  const size_t SZ_T = (size_t)DDIM * NBIG * 2;
  const size_t WS_NEED = SZ_T * 3 + (size_t)DDIM * DDIM * 2 + DDIM * 4;
  if (ws_size < WS_NEED) {
    fprintf(stderr, "kernel_launch: ws too small %zu < %zu\n", ws_size, WS_NEED);
    return;
  }
  char* ws = (char*)d_ws;
  unsigned short* KT   = (unsigned short*)ws;
  unsigned short* VT   = (unsigned short*)(ws + SZ_T);
  unsigned short* Kbf  = (unsigned short*)(ws + 2 * SZ_T);
  unsigned short* KVbf = (unsigned short*)(ws + 3 * SZ_T);
  float* ks            = (float*)(ws + 3 * SZ_T + (size_t)DDIM * DDIM * 2);

  float* ctx = (float*)d_out;
  float* nrm = ctx + (size_t)NBIG * DDIM;
  unsigned short* kvp = (unsigned short*)d_out;  // 32 MiB of bf16 partials in
                                                 // d_out scratch, overwritten by gemm2

  init_ks_kernel<<<(DDIM + 255) / 256, 256, 0, stream>>>(ksum, ks);
  prep_kernel<<<dim3((NBIG / 64) * (DDIM / 64), 2), 256, 0, stream>>>(k, v, KT, VT, Kbf, ks);
  // gemm1: bf16 kv partials = K^T V  (A=KT, B=VT, lda=ldb=NBIG, K-chunks of 4096)
  gemm256_kernel<true><<<dim3(DDIM / BN, DDIM / BM, SPLITK), 512, 0, stream>>>(
      KT, VT, kvp, NBIG, NBIG, NBIG / SPLITK, (long long)DDIM * DDIM);
  kvconv_kernel<<<(DDIM * DDIM) / (256 * 4), 256, 0, stream>>>(kvp, kvst, KVbf);
  // gemm2: ctx = K kv_new^T  (A=Kbf, B=KVbf, lda=ldb=DDIM, single K-chunk)
  gemm256_kernel<false><<<dim3(DDIM / BN, NBIG / BM, 1), 512, 0, stream>>>(
      Kbf, KVbf, ctx, DDIM, DDIM, DDIM, 0);
  norm_kernel<<<NBIG / 4, 256, 0, stream>>>(Kbf, ks, nrm);
}

// Round 18
// 374.711 us; speedup vs baseline: 1.0957x; 1.0081x over previous
//
#include <hip/hip_runtime.h>
#include <hip/hip_bf16.h>
#include <cstdio>
#include <cstdint>

// Problem constants (B=4, S=4096, D=2048)
#define NBIG 16384   // B*S
#define DDIM 2048
#define SPLITK 4     // gemm1 split-K

// 256^2 deep-pipelined GEMM geometry
#define BM 256
#define BN 256
#define BKT 64       // K-step per tile

typedef __attribute__((ext_vector_type(4))) float f32x4;
typedef __attribute__((ext_vector_type(8))) short bf16x8;

__device__ __forceinline__ unsigned short f2bf(float f) {
  union { float f; unsigned u; } v; v.f = f;
  return (unsigned short)((v.u + 0x7FFFu + ((v.u >> 16) & 1u)) >> 16); // RN-even
}

// global -> LDS direct copy, 16 B per lane. LDS dest is wave-uniform base;
// HW writes base + lane*16. Global source IS per-lane (swizzle goes there).
__device__ __forceinline__ void gll16(const void* g, void* l) {
  auto gp = reinterpret_cast<const __attribute__((address_space(1))) unsigned int*>(
      reinterpret_cast<uintptr_t>(g));
  auto lp = reinterpret_cast<__attribute__((address_space(3))) unsigned int*>(
      (unsigned int)reinterpret_cast<uintptr_t>(l));
  __builtin_amdgcn_global_load_lds(gp, lp, 16, 0, 0);
}

__device__ __forceinline__ void waitvm4() { asm volatile("s_waitcnt vmcnt(4)" ::: "memory"); }
__device__ __forceinline__ void waitvm0() { asm volatile("s_waitcnt vmcnt(0)" ::: "memory"); }
__device__ __forceinline__ void waitlgkm0() { asm volatile("s_waitcnt lgkmcnt(0)" ::: "memory"); }
#define SB0 __builtin_amdgcn_sched_barrier(0)

// bijective XCD swizzle (m204): all our GEMM grids have nwg % 8 == 0
__device__ __forceinline__ void xcd_swizzle(int& bx, int& by, int& bz) {
  const unsigned nx = gridDim.x, ny = gridDim.y;
  const unsigned nwg = nx * ny * gridDim.z;
  unsigned wg = blockIdx.x + nx * (blockIdx.y + ny * blockIdx.z);
  wg = (wg & 7u) * (nwg >> 3) + (wg >> 3);
  bx = wg % nx;
  unsigned r = wg / nx;
  by = r % ny;
  bz = r / ny;
}

// ---------------------------------------------------------------------------
// prep: 64x64 tiled transpose-convert f32 -> bf16.
//  blockIdx.y==0: k -> KT (D x NBIG) + K_bf (NBIG x D) + column-sum into ks
//  blockIdx.y==1: v -> VT (D x NBIG)
// ---------------------------------------------------------------------------
__global__ __launch_bounds__(256) void prep_kernel(
    const float* __restrict__ k, const float* __restrict__ v,
    unsigned short* __restrict__ KT, unsigned short* __restrict__ VT,
    unsigned short* __restrict__ Kbf, float* __restrict__ ks)
{
  __shared__ unsigned short sm[64][66];
  __shared__ float sks[64];
  const int t = threadIdx.x;
  const int tiles_d = DDIM / 64;
  const int n0 = (blockIdx.x / tiles_d) * 64;
  const int d0 = (blockIdx.x % tiles_d) * 64;
  const bool is_k = (blockIdx.y == 0);
  const float* __restrict__ src = is_k ? k : v;
  unsigned short* __restrict__ dstT = is_k ? KT : VT;

  const int r = t >> 4;         // 0..15
  const int c = (t & 15) * 4;   // 0..60

  if (t < 64) sks[t] = 0.f;
  __syncthreads();

  float a0 = 0.f, a1 = 0.f, a2 = 0.f, a3 = 0.f;
#pragma unroll
  for (int i = 0; i < 4; ++i) {
    const int row = i * 16 + r;
    f32x4 val = *reinterpret_cast<const f32x4*>(&src[(size_t)(n0 + row) * DDIM + d0 + c]);
    unsigned short b0 = f2bf(val.x), b1 = f2bf(val.y), b2 = f2bf(val.z), b3 = f2bf(val.w);
    sm[row][c + 0] = b0; sm[row][c + 1] = b1;
    sm[row][c + 2] = b2; sm[row][c + 3] = b3;
    if (is_k) {
      unsigned int p0 = (unsigned)b0 | ((unsigned)b1 << 16);
      unsigned int p1 = (unsigned)b2 | ((unsigned)b3 << 16);
      *reinterpret_cast<uint2*>(&Kbf[(size_t)(n0 + row) * DDIM + d0 + c]) = make_uint2(p0, p1);
      a0 += val.x; a1 += val.y; a2 += val.z; a3 += val.w;
    }
  }
  if (is_k) {
    atomicAdd(&sks[c + 0], a0);
    atomicAdd(&sks[c + 1], a1);
    atomicAdd(&sks[c + 2], a2);
    atomicAdd(&sks[c + 3], a3);
  }
  __syncthreads();

#pragma unroll
  for (int i = 0; i < 4; ++i) {
    const int rowp = i * 16 + r;
    unsigned int p0 = (unsigned)sm[c + 0][rowp] | ((unsigned)sm[c + 1][rowp] << 16);
    unsigned int p1 = (unsigned)sm[c + 2][rowp] | ((unsigned)sm[c + 3][rowp] << 16);
    *reinterpret_cast<uint2*>(&dstT[(size_t)(d0 + rowp) * NBIG + n0 + c]) = make_uint2(p0, p1);
  }
  if (is_k && t < 64) atomicAdd(&ks[d0 + t], sks[t]);
}

__global__ void init_ks_kernel(const float* __restrict__ ksum, float* __restrict__ ks) {
  int i = blockIdx.x * 256 + threadIdx.x;
  if (i < DDIM) ks[i] = ksum[i];
}

// ---------------------------------------------------------------------------
// gemm256: 256x256 tile, BK=64, 8 waves (2Mx4N), double-buffered LDS,
// m201-faithful 8-phase counted-vmcnt ring + T2 swizzle + T5 setprio + T1
// XCD swizzle. Per tile-pair (T=2it, buf0 / T+1, buf1), 8 phases; each phase:
//   [stage 1 half-tile] [ds_reads] SB0 barrier lgkm0 SB0 prio1 16-MFMA prio0
//   SB0 [vmcnt(4) at p3/p7] barrier
// Stage ring: p0/p1: A(T+1).h0/h1 ; p2/p3: B(T+2) ; p4/p5: A(T+2) ;
// p6/p7: B(T+3). vmcnt(4) at p3-end drains B(T+1),A(T+1) (p4's needs),
// leaves B(T+2) in flight; at p7-end drains B(T+2),A(T+2) (next p0's needs),
// leaves B(T+3) in flight. Never 0 mid-loop (T4). Cross-wave safety:
// vmcnt -> barrier -> dependent reads.
// BF16OUT: epilogue emits bf16 (gemm1 split partials) else f32 (gemm2 ctx).
// ---------------------------------------------------------------------------
template <bool BF16OUT>
__global__ __launch_bounds__(512, 2) void gemm256_kernel(
    const unsigned short* __restrict__ A, const unsigned short* __restrict__ B,
    void* __restrict__ Cv, int lda, int ldb, int kchunk, long long zstride)
{
  __shared__ unsigned short Abuf[2][BM * BKT];   // 32 KiB per buffer
  __shared__ unsigned short Bbuf[2][BN * BKT];   // total 128 KiB

  int bx, by, bz;
  xcd_swizzle(bx, by, bz);

  const int t = threadIdx.x, lane = t & 63, w = t >> 6;
  const int wm = w >> 2, wn = w & 3;            // 2 x 4 wave grid
  const int m0 = by * BM, n0 = bx * BN;
  const int kbeg = bz * kchunk;
  const int NT = kchunk / BKT;                  // 64 (gemm1) / 32 (gemm2)

  // staging: lane covers row (l>>3), swizzled source granule (l&7)^(l>>3)
  const int srow = lane >> 3;
  const int sgr  = (lane & 7) ^ srow;
  const unsigned short* Ag = A + (size_t)(m0 + srow) * lda + kbeg + sgr * 8;
  const unsigned short* Bg = B + (size_t)(n0 + srow) * ldb + kbeg + sgr * 8;

  // read-side swizzle constants: logical granule kk*4+hi, fetch slot ^=(row&7)
  const int hi = lane >> 4;              // 0..3
  const int lo7 = lane & 7;              // == row&7 for frag rows
  const int swz0 = ((0 + hi) ^ lo7) * 8; // kk=0, short offset
  const int swz1 = ((4 + hi) ^ lo7) * 8; // kk=1
  const int arow = (wm * 128 + (lane & 15)) * BKT;
  const int brow = (wn * 64 + (lane & 15)) * BKT;

  // stage one half (128 rows) of an operand tile: 2 x gll16 per thread
  auto stage_op = [&](const unsigned short* G, unsigned short* Lbase, int ld_,
                      int kt, int half) {
    const unsigned short* g = G + (size_t)(half * 128 + w * 16) * ld_ + (size_t)kt * BKT;
    unsigned short* l = Lbase + (half * 128 + w * 16) * BKT;
    gll16(g, l);
    gll16(g + (size_t)8 * ld_, l + 8 * BKT);
  };

  // prologue: B(0), A(0), B(1) (12 loads/thread); vmcnt(4) drains B0,A0,
  // leaves B1 (4 loads) in flight -> uniform loop from it=0.
  stage_op(Bg, Bbuf[0], ldb, 0, 0); stage_op(Bg, Bbuf[0], ldb, 0, 1);
  stage_op(Ag, Abuf[0], lda, 0, 0); stage_op(Ag, Abuf[0], lda, 0, 1);
  stage_op(Bg, Bbuf[1], ldb, 1, 0); stage_op(Bg, Bbuf[1], ldb, 1, 1);
  waitvm4();
  __builtin_amdgcn_s_barrier();
  SB0;

  f32x4 acc[8][4] = {};
  const int NI = NT / 2;

#pragma unroll 1
  for (int it = 0; it < NI; ++it) {
    const int T = it * 2;
    const bool pf2 = (T + 2 < NT);
    const bool pf3 = (T + 3 < NT);
    const bool last = (it == NI - 1);
    bf16x8 af[4][2], bA[2][2], bB[2][2];

    // ================= even tile T (buf 0) =================
    {
      const unsigned short* Al = Abuf[0];
      const unsigned short* Bl = Bbuf[0];

      // ---- p0: stage A(T+1).h0 ; read af(m0-3)+bA(n0-1) ; Q1
      stage_op(Ag, Abuf[1], lda, T + 1, 0);
#pragma unroll
      for (int m = 0; m < 4; ++m) {
        af[m][0] = *reinterpret_cast<const bf16x8*>(Al + arow + m * 16 * BKT + swz0);
        af[m][1] = *reinterpret_cast<const bf16x8*>(Al + arow + m * 16 * BKT + swz1);
      }
#pragma unroll
      for (int n = 0; n < 2; ++n) {
        bA[n][0] = *reinterpret_cast<const bf16x8*>(Bl + brow + n * 16 * BKT + swz0);
        bA[n][1] = *reinterpret_cast<const bf16x8*>(Bl + brow + n * 16 * BKT + swz1);
      }
      SB0; __builtin_amdgcn_s_barrier(); waitlgkm0(); SB0;
      __builtin_amdgcn_s_setprio(1);
#pragma unroll
      for (int kk = 0; kk < 2; ++kk)
#pragma unroll
        for (int m = 0; m < 4; ++m)
#pragma unroll
          for (int n = 0; n < 2; ++n)
            acc[m][n] = __builtin_amdgcn_mfma_f32_16x16x32_bf16(af[m][kk], bA[n][kk], acc[m][n], 0, 0, 0);
      __builtin_amdgcn_s_setprio(0);
      SB0; __builtin_amdgcn_s_barrier(); SB0;

      // ---- p1: stage A(T+1).h1 ; read bB(n2-3) ; Q2
      stage_op(Ag, Abuf[1], lda, T + 1, 1);
#pragma unroll
      for (int n = 0; n < 2; ++n) {
        bB[n][0] = *reinterpret_cast<const bf16x8*>(Bl + brow + (32 + n * 16) * BKT + swz0);
        bB[n][1] = *reinterpret_cast<const bf16x8*>(Bl + brow + (32 + n * 16) * BKT + swz1);
      }
      SB0; __builtin_amdgcn_s_barrier(); waitlgkm0(); SB0;
      __builtin_amdgcn_s_setprio(1);
#pragma unroll
      for (int kk = 0; kk < 2; ++kk)
#pragma unroll
        for (int m = 0; m < 4; ++m)
#pragma unroll
          for (int n = 0; n < 2; ++n)
            acc[m][2 + n] = __builtin_amdgcn_mfma_f32_16x16x32_bf16(af[m][kk], bB[n][kk], acc[m][2 + n], 0, 0, 0);
      __builtin_amdgcn_s_setprio(0);
      SB0; __builtin_amdgcn_s_barrier(); SB0;

      // ---- p2: stage B(T+2).h0 ; read af(m4-7) ; Q3
      if (pf2) stage_op(Bg, Bbuf[0], ldb, T + 2, 0);
#pragma unroll
      for (int m = 0; m < 4; ++m) {
        af[m][0] = *reinterpret_cast<const bf16x8*>(Al + arow + (64 + m * 16) * BKT + swz0);
        af[m][1] = *reinterpret_cast<const bf16x8*>(Al + arow + (64 + m * 16) * BKT + swz1);
      }
      SB0; __builtin_amdgcn_s_barrier(); waitlgkm0(); SB0;
      __builtin_amdgcn_s_setprio(1);
#pragma unroll
      for (int kk = 0; kk < 2; ++kk)
#pragma unroll
        for (int m = 0; m < 4; ++m)
#pragma unroll
          for (int n = 0; n < 2; ++n)
            acc[4 + m][n] = __builtin_amdgcn_mfma_f32_16x16x32_bf16(af[m][kk], bA[n][kk], acc[4 + m][n], 0, 0, 0);
      __builtin_amdgcn_s_setprio(0);
      SB0; __builtin_amdgcn_s_barrier(); SB0;

      // ---- p3: stage B(T+2).h1 ; Q4 ; vmcnt(4) ; bar
      if (pf2) stage_op(Bg, Bbuf[0], ldb, T + 2, 1);
      SB0; __builtin_amdgcn_s_barrier(); SB0;
      __builtin_amdgcn_s_setprio(1);
#pragma unroll
      for (int kk = 0; kk < 2; ++kk)
#pragma unroll
        for (int m = 0; m < 4; ++m)
#pragma unroll
          for (int n = 0; n < 2; ++n)
            acc[4 + m][2 + n] = __builtin_amdgcn_mfma_f32_16x16x32_bf16(af[m][kk], bB[n][kk], acc[4 + m][2 + n], 0, 0, 0);
      __builtin_amdgcn_s_setprio(0);
      SB0;
      if (last) waitvm0();   // tail: everything must land for p4-p7
      else      waitvm4();   // drains B(T+1),A(T+1); B(T+2) stays in flight
      __builtin_amdgcn_s_barrier();
      SB0;
    }

    // ================= odd tile T+1 (buf 1) =================
    {
      const unsigned short* Al = Abuf[1];
      const unsigned short* Bl = Bbuf[1];

      // ---- p4: stage A(T+2).h0 ; read af(m0-3)+bA ; Q1'
      if (pf2) stage_op(Ag, Abuf[0], lda, T + 2, 0);
#pragma unroll
      for (int m = 0; m < 4; ++m) {
        af[m][0] = *reinterpret_cast<const bf16x8*>(Al + arow + m * 16 * BKT + swz0);
        af[m][1] = *reinterpret_cast<const bf16x8*>(Al + arow + m * 16 * BKT + swz1);
      }
#pragma unroll
      for (int n = 0; n < 2; ++n) {
        bA[n][0] = *reinterpret_cast<const bf16x8*>(Bl + brow + n * 16 * BKT + swz0);
        bA[n][1] = *reinterpret_cast<const bf16x8*>(Bl + brow + n * 16 * BKT + swz1);
      }
      SB0; __builtin_amdgcn_s_barrier(); waitlgkm0(); SB0;
      __builtin_amdgcn_s_setprio(1);
#pragma unroll
      for (int kk = 0; kk < 2; ++kk)
#pragma unroll
        for (int m = 0; m < 4; ++m)
#pragma unroll
          for (int n = 0; n < 2; ++n)
            acc[m][n] = __builtin_amdgcn_mfma_f32_16x16x32_bf16(af[m][kk], bA[n][kk], acc[m][n], 0, 0, 0);
      __builtin_amdgcn_s_setprio(0);
      SB0; __builtin_amdgcn_s_barrier(); SB0;

      // ---- p5: stage A(T+2).h1 ; read bB ; Q2'
      if (pf2) stage_op(Ag, Abuf[0], lda, T + 2, 1);
#pragma unroll
      for (int n = 0; n < 2; ++n) {
        bB[n][0] = *reinterpret_cast<const bf16x8*>(Bl + brow + (32 + n * 16) * BKT + swz0);
        bB[n][1] = *reinterpret_cast<const bf16x8*>(Bl + brow + (32 + n * 16) * BKT + swz1);
      }
      SB0; __builtin_amdgcn_s_barrier(); waitlgkm0(); SB0;
      __builtin_amdgcn_s_setprio(1);
#pragma unroll
      for (int kk = 0; kk < 2; ++kk)
#pragma unroll
        for (int m = 0; m < 4; ++m)
#pragma unroll
          for (int n = 0; n < 2; ++n)
            acc[m][2 + n] = __builtin_amdgcn_mfma_f32_16x16x32_bf16(af[m][kk], bB[n][kk], acc[m][2 + n], 0, 0, 0);
      __builtin_amdgcn_s_setprio(0);
      SB0; __builtin_amdgcn_s_barrier(); SB0;

      // ---- p6: stage B(T+3).h0 ; read af(m4-7) ; Q3'
      if (pf3) stage_op(Bg, Bbuf[1], ldb, T + 3, 0);
#pragma unroll
      for (int m = 0; m < 4; ++m) {
        af[m][0] = *reinterpret_cast<const bf16x8*>(Al + arow + (64 + m * 16) * BKT + swz0);
        af[m][1] = *reinterpret_cast<const bf16x8*>(Al + arow + (64 + m * 16) * BKT + swz1);
      }
      SB0; __builtin_amdgcn_s_barrier(); waitlgkm0(); SB0;
      __builtin_amdgcn_s_setprio(1);
#pragma unroll
      for (int kk = 0; kk < 2; ++kk)
#pragma unroll
        for (int m = 0; m < 4; ++m)
#pragma unroll
          for (int n = 0; n < 2; ++n)
            acc[4 + m][n] = __builtin_amdgcn_mfma_f32_16x16x32_bf16(af[m][kk], bA[n][kk], acc[4 + m][n], 0, 0, 0);
      __builtin_amdgcn_s_setprio(0);
      SB0; __builtin_amdgcn_s_barrier(); SB0;

      // ---- p7: stage B(T+3).h1 ; Q4' ; vmcnt(4) ; bar
      if (pf3) stage_op(Bg, Bbuf[1], ldb, T + 3, 1);
      SB0; __builtin_amdgcn_s_barrier(); SB0;
      __builtin_amdgcn_s_setprio(1);
#pragma unroll
      for (int kk = 0; kk < 2; ++kk)
#pragma unroll
        for (int m = 0; m < 4; ++m)
#pragma unroll
          for (int n = 0; n < 2; ++n)
            acc[4 + m][2 + n] = __builtin_amdgcn_mfma_f32_16x16x32_bf16(af[m][kk], bB[n][kk], acc[4 + m][2 + n], 0, 0, 0);
      __builtin_amdgcn_s_setprio(0);
      SB0;
      if (!last) {
        waitvm4();   // drains B(T+2),A(T+2) for next p0; B(T+3) in flight
        __builtin_amdgcn_s_barrier();
        SB0;
      }
    }
  }
  waitvm0();   // hygiene: no DMA pending into LDS at epilogue/endpgm

  // epilogue: C/D layout col=lane&15, row=hi*4+j
  const int crow0 = m0 + wm * 128 + hi * 4;
  const int ccol0 = n0 + wn * 64 + (lane & 15);
  if (BF16OUT) {
    unsigned short* Cz = (unsigned short*)Cv + (size_t)bz * zstride;
#pragma unroll
    for (int m = 0; m < 8; ++m)
#pragma unroll
      for (int n = 0; n < 4; ++n)
#pragma unroll
        for (int j = 0; j < 4; ++j)
          Cz[(size_t)(crow0 + m * 16 + j) * DDIM + ccol0 + n * 16] = f2bf(acc[m][n][j]);
  } else {
    float* Cz = (float*)Cv + (size_t)bz * zstride;
#pragma unroll
    for (int m = 0; m < 8; ++m)
#pragma unroll
      for (int n = 0; n < 4; ++n)
#pragma unroll
        for (int j = 0; j < 4; ++j)
          Cz[(size_t)(crow0 + m * 16 + j) * DDIM + ccol0 + n * 16] = acc[m][n][j];
  }
}

// kv_bf[i] = bf16(kv_state[i] + sum_z bf16_partial[z][i])
__global__ __launch_bounds__(256) void kvconv_kernel(
    const unsigned short* __restrict__ kvp, const float* __restrict__ kvst,
    unsigned short* __restrict__ kvbf)
{
  size_t i = ((size_t)blockIdx.x * 256 + threadIdx.x) * 4;
  f32x4 s = *reinterpret_cast<const f32x4*>(&kvst[i]);
#pragma unroll
  for (int z = 0; z < SPLITK; ++z) {
    ushort4 p = *reinterpret_cast<const ushort4*>(&kvp[(size_t)z * DDIM * DDIM + i]);
    union { unsigned u; float f; } c0, c1, c2, c3;
    c0.u = (unsigned)p.x << 16; c1.u = (unsigned)p.y << 16;
    c2.u = (unsigned)p.z << 16; c3.u = (unsigned)p.w << 16;
    s.x += c0.f; s.y += c1.f; s.z += c2.f; s.w += c3.f;
  }
  unsigned int p0 = (unsigned)f2bf(s.x) | ((unsigned)f2bf(s.y) << 16);
  unsigned int p1 = (unsigned)f2bf(s.z) | ((unsigned)f2bf(s.w) << 16);
  *reinterpret_cast<uint2*>(&kvbf[i]) = make_uint2(p0, p1);
}

// normalizer[n] = sum_d Kbf[n,d] * ks_new[d]  (bf16 k, f32 ks; wave per row)
__global__ __launch_bounds__(256) void norm_kernel(
    const unsigned short* __restrict__ Kbf, const float* __restrict__ ks,
    float* __restrict__ out)
{
  const int lane = threadIdx.x & 63;
  const int w = threadIdx.x >> 6;
  const int row = blockIdx.x * 4 + w;
  const unsigned short* kr = Kbf + (size_t)row * DDIM;
  float s = 0.f;
#pragma unroll
  for (int i = 0; i < 4; ++i) {
    bf16x8 a = *reinterpret_cast<const bf16x8*>(&kr[i * 512 + lane * 8]);
    f32x4 b0 = *reinterpret_cast<const f32x4*>(&ks[i * 512 + lane * 8]);
    f32x4 b1 = *reinterpret_cast<const f32x4*>(&ks[i * 512 + lane * 8 + 4]);
    float af[8];
#pragma unroll
    for (int j = 0; j < 8; ++j) {
      union { unsigned u; float f; } cv;
      cv.u = ((unsigned)(unsigned short)a[j]) << 16;
      af[j] = cv.f;
    }
    s += af[0] * b0.x + af[1] * b0.y + af[2] * b0.z + af[3] * b0.w
       + af[4] * b1.x + af[5] * b1.y + af[6] * b1.z + af[7] * b1.w;
  }
  for (int off = 32; off; off >>= 1) s += __shfl_down(s, off, 64);
  if (lane == 0) out[row] = s;
}

extern "C" void kernel_launch(void* const* d_in, const int* in_sizes, int n_in,
                              void* d_out, int out_size, void* d_ws, size_t ws_size,
                              hipStream_t stream) {
  const float* k    = (const float*)d_in[0];
  const float* v    = (const float*)d_in[1];
  const float* kvst = (const float*)d_in[2];
  const float* ksum = (const float*)d_in[3];

  // ws layout: KT (64Mi) | VT (64Mi) | K_bf (64Mi) | kv_bf (8Mi) | ks (8Ki)
  const size_t SZ_T = (size_t)DDIM * NBIG * 2;
  const size_t WS_NEED = SZ_T * 3 + (size_t)DDIM * DDIM * 2 + DDIM * 4;
  if (ws_size < WS_NEED) {
    fprintf(stderr, "kernel_launch: ws too small %zu < %zu\n", ws_size, WS_NEED);
    return;
  }
  char* ws = (char*)d_ws;
  unsigned short* KT   = (unsigned short*)ws;
  unsigned short* VT   = (unsigned short*)(ws + SZ_T);
  unsigned short* Kbf  = (unsigned short*)(ws + 2 * SZ_T);
  unsigned short* KVbf = (unsigned short*)(ws + 3 * SZ_T);
  float* ks            = (float*)(ws + 3 * SZ_T + (size_t)DDIM * DDIM * 2);

  float* ctx = (float*)d_out;
  float* nrm = ctx + (size_t)NBIG * DDIM;
  unsigned short* kvp = (unsigned short*)d_out;  // 32 MiB of bf16 partials in
                                                 // d_out scratch, overwritten by gemm2

  init_ks_kernel<<<(DDIM + 255) / 256, 256, 0, stream>>>(ksum, ks);
  prep_kernel<<<dim3((NBIG / 64) * (DDIM / 64), 2), 256, 0, stream>>>(k, v, KT, VT, Kbf, ks);
  // gemm1: bf16 kv partials = K^T V  (A=KT, B=VT, lda=ldb=NBIG, K-chunks of 4096)
  gemm256_kernel<true><<<dim3(DDIM / BN, DDIM / BM, SPLITK), 512, 0, stream>>>(
      KT, VT, kvp, NBIG, NBIG, NBIG / SPLITK, (long long)DDIM * DDIM);
  kvconv_kernel<<<(DDIM * DDIM) / (256 * 4), 256, 0, stream>>>(kvp, kvst, KVbf);
  // gemm2: ctx = K kv_new^T  (A=Kbf, B=KVbf, lda=ldb=DDIM, single K-chunk)
  gemm256_kernel<false><<<dim3(DDIM / BN, NBIG / BM, 1), 512, 0, stream>>>(
      Kbf, KVbf, ctx, DDIM, DDIM, DDIM, 0);
  norm_kernel<<<NBIG / 4, 256, 0, stream>>>(Kbf, ks, nrm);
}